// Round 5
// baseline (235.138 us; speedup 1.0000x reference)
//
#include <hip/hip_runtime.h>

#define NN 50000
#define EE 800000
#define DD 128
#define BN_EPS 1e-5f
#define XCONV_B 3125    // N*D/8/256
#define BIN_BLOCKS 200
#define BIN_EDGES 4000  // per block; 200*4000 == EE
#define RCAP 64         // per-row CSR slot capacity (mean 16, +12 sigma)
#define NAGG 6250       // 50000/8: 8-row groups per agg block (1 wave)
#define NREP 32         // BN-stat replica count
#define MLP_B 391       // ceil(50000/128) fused-MLP blocks
#define LDA 136         // padded LDS tile stride (bf16)

typedef __attribute__((ext_vector_type(8))) short bf16x8;
typedef __attribute__((ext_vector_type(4))) float f32x4;
typedef __attribute__((ext_vector_type(8))) unsigned short u16x8;

__device__ inline unsigned short f2bf(float f) {  // RNE fp32 -> bf16
  unsigned int u = __float_as_uint(f);
  u = (u + 0x7fffu + ((u >> 16) & 1u)) >> 16;
  return (unsigned short)u;
}
__device__ inline float bf2f(unsigned short b) {
  return __uint_as_float(((unsigned int)b) << 16);
}
__device__ inline float ldw(const float* p) {
  return __hip_atomic_load(p, __ATOMIC_RELAXED, __HIP_MEMORY_SCOPE_AGENT);
}
__device__ inline void stw(float* p, float v) {
  __hip_atomic_store(p, v, __ATOMIC_RELAXED, __HIP_MEMORY_SCOPE_AGENT);
}

// ---------------------------------------------------------------------------
// R15. Lessons pinned: launch gap ~13us (R7-R9); __threadfence = L2 flush
// storm (R12); wave concurrency for the random gather caps at ~9-10/CU
// regardless of shape (R11/R13/R14); per-iteration vmcnt(0) drains kill the
// gather pipeline; 4x per-pass re-sort was pure overhead; agent-scope loads
// of broadcast values bypass L2 -> 391-block read storm on 2 lines (R14
// k_mlp 63us @ 6% VALUBusy suspect).
// This round:
//  * k_binrow: CSR-fixed placement csr16[row*64 + atomicAdd(rcnt[row])] —
//    row-sorted edge layout in ONE pass; agg-side sort eliminated.
//  * k_agg: 1-wave blocks, 8 lanes/row x 8 rows, pass-sliced xq (4 x 3.2MB
//    L2-resident), 8-slot STATICALLY-NAMED rotating load pipeline with
//    col-vector loads hoisted one chunk ahead -> in-order vmem returns mean
//    all waits are partial (vmcnt(N)), never full drains; 64 edges in
//    flight per wave.
//  * k_mlp: post-spin scale/shift via NORMAL loads (first-touch lines,
//    winner stored to coherence point before flag; L2-broadcast), s_sleep(8).
// 4 dispatches: prep, binrow, agg, mlp.
// d_out scratch: rcnt[50000] | xq(4.0M..16.8M) | csr16(16.8M..23.2M) |
//   W1b,W2b(23.28M) | reps(23.5M) — all dead before the final out write.
// d_ws: aggb bf16 [0,12.8M) | scale1,shift1,scale2,shift2 | syncw[4].
// ---------------------------------------------------------------------------

// K0: fused prep — x->bf16 column-blocked xq, W1b, W2b, zero rcnt/reps/syncw
__global__ __launch_bounds__(256) void k_prep(const float* __restrict__ x,
                                              const float* __restrict__ W1,
                                              const float* __restrict__ W2,
                                              unsigned short* __restrict__ xq,
                                              unsigned short* __restrict__ W1b,
                                              unsigned short* __restrict__ W2b,
                                              int* __restrict__ rcnt,
                                              float* __restrict__ reps,
                                              int* __restrict__ syncw) {
  const int b = blockIdx.x;
  const int t = threadIdx.x;
  if (b < XCONV_B) {
    const int gid = b * 256 + t;
    const float4 v0 = ((const float4*)x)[gid * 2];
    const float4 v1 = ((const float4*)x)[gid * 2 + 1];
    ushort4 o0, o1;
    o0.x = f2bf(v0.x); o0.y = f2bf(v0.y); o0.z = f2bf(v0.z); o0.w = f2bf(v0.w);
    o1.x = f2bf(v1.x); o1.y = f2bf(v1.y); o1.z = f2bf(v1.z); o1.w = f2bf(v1.w);
    const int node = gid >> 4;
    const int c0 = (gid & 15) * 8;
    const size_t dst = (size_t)(c0 >> 5) * (NN * 32) + node * 32 + (c0 & 31);
    *(ushort4*)(xq + dst) = o0;
    *(ushort4*)(xq + dst + 4) = o1;
    if (gid < NN) rcnt[gid] = 0;
    if (gid < 4 * NREP * DD) reps[gid] = 0.0f;
    if (gid < 4) syncw[gid] = 0;  // done1, flag1, done2, flag2
  } else if (b < XCONV_B + 16) {
    const int gid = (b - XCONV_B) * 256 + t;
    const float4 v = ((const float4*)W1)[gid];
    ushort4 o;
    o.x = f2bf(v.x); o.y = f2bf(v.y); o.z = f2bf(v.z); o.w = f2bf(v.w);
    ((ushort4*)W1b)[gid] = o;
  } else {
    const int gid = (b - XCONV_B - 16) * 256 + t;
    const float4 v = ((const float4*)W2)[gid];
    ushort4 o;
    o.x = f2bf(v.x); o.y = f2bf(v.y); o.z = f2bf(v.z); o.w = f2bf(v.w);
    ((ushort4*)W2b)[gid] = o;
  }
}

// K1: CSR-fixed binning — one pass, row-sorted layout, no LDS.
__global__ __launch_bounds__(256) void k_binrow(const int* __restrict__ rows,
                                                const int* __restrict__ cols,
                                                int* __restrict__ rcnt,
                                                unsigned short* __restrict__ csr) {
  const int t = threadIdx.x;
  const int e0 = blockIdx.x * BIN_EDGES;
#pragma unroll
  for (int k = 0; k < 16; ++k) {
    const int li = t + k * 256;
    if (li < BIN_EDGES) {
      const int r = rows[e0 + li];
      const int c = cols[e0 + li];
      const int p = atomicAdd(&rcnt[r], 1);
      if (p < RCAP)  // statistically impossible overflow; memory-safety clamp
        csr[(size_t)r * RCAP + p] = (unsigned short)c;
    }
  }
}

// K2: pass-sliced gather. Block = 1 wave; group g (8 lanes) owns row
// bk*8+g, cols [q*32, q*32+32). 8-slot statically-named rotating pipeline:
// col-vec for chunk k+1 loaded during chunk k (in-order vmem returns =>
// the wait for slot j is partial, never a drain). 64 edges in flight/wave.
__global__ __launch_bounds__(64) void k_agg(
    const unsigned short* __restrict__ xq, const float* __restrict__ eps,
    const int* __restrict__ rcnt, const unsigned short* __restrict__ csr,
    unsigned short* __restrict__ aggb) {
  const int t = threadIdx.x;
  const int id = blockIdx.x;
  const int q = id / NAGG;       // consecutive ids share a pass
  const int bk = id - q * NAGG;
  const int g = t >> 3;          // group 0..7
  const int l8 = t & 7;
  const int gb = t & 56;         // group's base lane
  const int r = bk * 8 + g;      // my row
  int n = rcnt[r];
  n = n < RCAP ? n : RCAP;
  const unsigned short* xqq = xq + (size_t)q * ((size_t)NN * 32);
  const unsigned short* crow = csr + (size_t)r * RCAP;
  const int lo = l8 * 4;
  const float s = 1.0f + eps[0];
  const ushort4 sv = *(const ushort4*)(xqq + (size_t)r * 32 + lo);
  float a0 = s * bf2f(sv.x), a1 = s * bf2f(sv.y),
        a2 = s * bf2f(sv.z), a3 = s * bf2f(sv.w);

#define GLD(c) (*(const ushort4*)(xqq + (size_t)(c) * 32 + lo))
#define CONS(p) { a0 += bf2f(p.x); a1 += bf2f(p.y); a2 += bf2f(p.z); a3 += bf2f(p.w); }

  int i = 0;
  ushort4 p0, p1, p2, p3, p4, p5, p6, p7;
  if (n >= 8) {
    const unsigned cv = (unsigned)crow[l8];  // cols chunk0 (lane-vector)
    p0 = GLD(__shfl(cv, gb + 0)); p1 = GLD(__shfl(cv, gb + 1));
    p2 = GLD(__shfl(cv, gb + 2)); p3 = GLD(__shfl(cv, gb + 3));
    p4 = GLD(__shfl(cv, gb + 4)); p5 = GLD(__shfl(cv, gb + 5));
    p6 = GLD(__shfl(cv, gb + 6)); p7 = GLD(__shfl(cv, gb + 7));
    unsigned cv2 = (8 + l8 < n) ? (unsigned)crow[8 + l8] : 0u;  // chunk1 cols
    for (i = 8; i + 8 <= n; i += 8) {
      const unsigned cv3 =
          (i + 8 + l8 < n) ? (unsigned)crow[i + 8 + l8] : 0u;  // chunk k+2
      CONS(p0); p0 = GLD(__shfl(cv2, gb + 0));
      CONS(p1); p1 = GLD(__shfl(cv2, gb + 1));
      CONS(p2); p2 = GLD(__shfl(cv2, gb + 2));
      CONS(p3); p3 = GLD(__shfl(cv2, gb + 3));
      CONS(p4); p4 = GLD(__shfl(cv2, gb + 4));
      CONS(p5); p5 = GLD(__shfl(cv2, gb + 5));
      CONS(p6); p6 = GLD(__shfl(cv2, gb + 6));
      CONS(p7); p7 = GLD(__shfl(cv2, gb + 7));
      cv2 = cv3;
    }
    CONS(p0); CONS(p1); CONS(p2); CONS(p3);
    CONS(p4); CONS(p5); CONS(p6); CONS(p7);
  }
  const int rem = n - i;  // group-uniform => branches below are wave-safe
  if (rem > 0) {
    const unsigned tv = (i + l8 < n) ? (unsigned)crow[i + l8] : 0u;
    if (rem > 0) p0 = GLD(__shfl(tv, gb + 0));
    if (rem > 1) p1 = GLD(__shfl(tv, gb + 1));
    if (rem > 2) p2 = GLD(__shfl(tv, gb + 2));
    if (rem > 3) p3 = GLD(__shfl(tv, gb + 3));
    if (rem > 4) p4 = GLD(__shfl(tv, gb + 4));
    if (rem > 5) p5 = GLD(__shfl(tv, gb + 5));
    if (rem > 6) p6 = GLD(__shfl(tv, gb + 6));
    if (rem > 0) CONS(p0);
    if (rem > 1) CONS(p1);
    if (rem > 2) CONS(p2);
    if (rem > 3) CONS(p3);
    if (rem > 4) CONS(p4);
    if (rem > 5) CONS(p5);
    if (rem > 6) CONS(p6);
  }
#undef GLD
#undef CONS
  ushort4 o;
  o.x = f2bf(a0); o.y = f2bf(a1); o.z = f2bf(a2); o.w = f2bf(a3);
  *(ushort4*)(aggb + (size_t)r * DD + q * 32 + lo) = o;
}

// K3: fused MLP (R4 structure, proven): GEMM1 -> BN1 stats -> spin1 ->
// BN1+ReLU -> GEMM2 -> BN2 stats -> spin2 -> BN2+ReLU -> fp32 out.
// Capacity-safe spin: __launch_bounds__(256,2) + 36KB LDS => >=2 blocks/CU
// co-resident (512 slots >= 391). Fence-free (R12). NEW: post-spin
// scale/shift reads are NORMAL loads (L2-cacheable broadcast).
__global__ __launch_bounds__(256, 2) void k_mlp(
    const unsigned short* __restrict__ aggb, float* __restrict__ sum1r,
    float* __restrict__ sumsq1r, const float* __restrict__ g1,
    const float* __restrict__ be1, const unsigned short* __restrict__ W1b,
    const float* __restrict__ b1, const unsigned short* __restrict__ W2b,
    const float* __restrict__ b2, float* __restrict__ sum2r,
    float* __restrict__ sumsq2r, const float* __restrict__ g2,
    const float* __restrict__ be2, float* __restrict__ scale1,
    float* __restrict__ shift1, float* __restrict__ scale2,
    float* __restrict__ shift2, int* __restrict__ syncw,
    float* __restrict__ out) {
  __shared__ unsigned short sT[128 * LDA];  // 34.8KB: agg tile, then h1 tile
  __shared__ float lsc[DD];
  __shared__ float lsh[DD];
  __shared__ int amlast;
  const int tid = threadIdx.x;
  const int bk = blockIdx.x;
  const int wv = tid >> 6;
  const int lane = tid & 63;
  const int quad = lane >> 4;
  const int l16 = lane & 15;
  const int rowq = bk * 128 + wv * 32 + quad * 4;

  // stage agg rows [bk*128, +128) -> sT (clamped; pad rows finite)
#pragma unroll
  for (int it = 0; it < 8; ++it) {
    const int idx = it * 256 + tid;
    const int row = idx >> 4, seg = idx & 15;
    int grow = bk * 128 + row;
    grow = grow < NN ? grow : NN - 1;
    *(u16x8*)&sT[row * LDA + seg * 8] =
        *(const u16x8*)(aggb + (size_t)grow * DD + seg * 8);
  }
  __syncthreads();

  // ---- GEMM1
  f32x4 acc[2][8];
#pragma unroll
  for (int m = 0; m < 2; ++m)
#pragma unroll
    for (int n = 0; n < 8; ++n) acc[m][n] = (f32x4){0.f, 0.f, 0.f, 0.f};
#pragma unroll
  for (int kk = 0; kk < 4; ++kk) {
    const bf16x8 a0 =
        *(const bf16x8*)&sT[(wv * 32 + l16) * LDA + kk * 32 + quad * 8];
    const bf16x8 a1 =
        *(const bf16x8*)&sT[(wv * 32 + 16 + l16) * LDA + kk * 32 + quad * 8];
#pragma unroll
    for (int n = 0; n < 8; ++n) {
      const bf16x8 bf = *(const bf16x8*)(W1b + (size_t)(n * 16 + l16) * DD +
                                         kk * 32 + quad * 8);
      acc[0][n] = __builtin_amdgcn_mfma_f32_16x16x32_bf16(a0, bf, acc[0][n], 0, 0, 0);
      acc[1][n] = __builtin_amdgcn_mfma_f32_16x16x32_bf16(a1, bf, acc[1][n], 0, 0, 0);
    }
  }
  // bias + BN1 replica stats (guard pad rows)
#pragma unroll
  for (int n = 0; n < 8; ++n) {
    const int col = n * 16 + l16;
    const float bv = b1[col];
    float sv = 0.f, qv = 0.f;
#pragma unroll
    for (int m = 0; m < 2; ++m)
#pragma unroll
      for (int r = 0; r < 4; ++r) {
        const float o = acc[m][n][r] + bv;
        acc[m][n][r] = o;
        if (rowq + m * 16 + r < NN) { sv += o; qv += o * o; }
      }
    sv += __shfl_xor(sv, 16); qv += __shfl_xor(qv, 16);
    sv += __shfl_xor(sv, 32); qv += __shfl_xor(qv, 32);
    if (quad == 0) {
      const int rep = (bk & (NREP - 1)) * DD;
      atomicAdd(&sum1r[rep + col], sv);
      atomicAdd(&sumsq1r[rep + col], qv);
    }
  }
  __syncthreads();  // stats RMWs drained; sT(agg) dead -> becomes h1 tile
  // h1 -> sT (bf16, rounding identical to the old h1b path)
#pragma unroll
  for (int m = 0; m < 2; ++m)
#pragma unroll
    for (int n = 0; n < 8; ++n)
#pragma unroll
      for (int r = 0; r < 4; ++r)
        sT[(wv * 32 + m * 16 + quad * 4 + r) * LDA + n * 16 + l16] =
            f2bf(acc[m][n][r]);

  // done1 / winner collapse / flag1 (fence-free)
  if (tid == 0) amlast = (atomicAdd(&syncw[0], 1) == MLP_B - 1) ? 1 : 0;
  __syncthreads();
  if (amlast) {
    if (tid < DD) {
      float sm = 0.f, qm = 0.f;
#pragma unroll
      for (int r = 0; r < NREP; ++r) {
        sm += ldw(&sum1r[r * DD + tid]);
        qm += ldw(&sumsq1r[r * DD + tid]);
      }
      const float inv_n = 1.0f / (float)NN;
      const float mean = sm * inv_n;
      const float var = qm * inv_n - mean * mean;
      const float sc = g1[tid] * rsqrtf(var + BN_EPS);
      stw(&scale1[tid], sc);
      stw(&shift1[tid], be1[tid] - mean * sc);
      lsc[tid] = sc;
      lsh[tid] = be1[tid] - mean * sc;
    }
    __syncthreads();  // drain scale/shift stores before flag
    if (tid == 0)
      __hip_atomic_store(&syncw[1], 1, __ATOMIC_RELAXED, __HIP_MEMORY_SCOPE_AGENT);
  } else {
    if (tid == 0) {
      while (__hip_atomic_load(&syncw[1], __ATOMIC_RELAXED,
                               __HIP_MEMORY_SCOPE_AGENT) == 0)
        __builtin_amdgcn_s_sleep(8);
    }
    __syncthreads();  // spinner done -> flag set, winner stores visible
    if (tid < DD) {   // NORMAL loads: first-touch lines, L2-broadcast
      lsc[tid] = scale1[tid];
      lsh[tid] = shift1[tid];
    }
  }
  __syncthreads();

  // ---- GEMM2: A = relu(BN1(h1)) on the fly from sT
  f32x4 acc2[2][8];
#pragma unroll
  for (int m = 0; m < 2; ++m)
#pragma unroll
    for (int n = 0; n < 8; ++n) acc2[m][n] = (f32x4){0.f, 0.f, 0.f, 0.f};
#pragma unroll
  for (int kk = 0; kk < 4; ++kk) {
    const int kb = kk * 32 + quad * 8;
    const float4 s0 = *(const float4*)&lsc[kb];
    const float4 s1 = *(const float4*)&lsc[kb + 4];
    const float4 h0 = *(const float4*)&lsh[kb];
    const float4 h1v = *(const float4*)&lsh[kb + 4];
    const u16x8 x0 = *(const u16x8*)&sT[(wv * 32 + l16) * LDA + kb];
    const u16x8 x1 = *(const u16x8*)&sT[(wv * 32 + 16 + l16) * LDA + kb];
    bf16x8 af0, af1;
    af0[0] = (short)f2bf(fmaxf(fmaf(s0.x, bf2f(x0[0]), h0.x), 0.f));
    af0[1] = (short)f2bf(fmaxf(fmaf(s0.y, bf2f(x0[1]), h0.y), 0.f));
    af0[2] = (short)f2bf(fmaxf(fmaf(s0.z, bf2f(x0[2]), h0.z), 0.f));
    af0[3] = (short)f2bf(fmaxf(fmaf(s0.w, bf2f(x0[3]), h0.w), 0.f));
    af0[4] = (short)f2bf(fmaxf(fmaf(s1.x, bf2f(x0[4]), h1v.x), 0.f));
    af0[5] = (short)f2bf(fmaxf(fmaf(s1.y, bf2f(x0[5]), h1v.y), 0.f));
    af0[6] = (short)f2bf(fmaxf(fmaf(s1.z, bf2f(x0[6]), h1v.z), 0.f));
    af0[7] = (short)f2bf(fmaxf(fmaf(s1.w, bf2f(x0[7]), h1v.w), 0.f));
    af1[0] = (short)f2bf(fmaxf(fmaf(s0.x, bf2f(x1[0]), h0.x), 0.f));
    af1[1] = (short)f2bf(fmaxf(fmaf(s0.y, bf2f(x1[1]), h0.y), 0.f));
    af1[2] = (short)f2bf(fmaxf(fmaf(s0.z, bf2f(x1[2]), h0.z), 0.f));
    af1[3] = (short)f2bf(fmaxf(fmaf(s0.w, bf2f(x1[3]), h0.w), 0.f));
    af1[4] = (short)f2bf(fmaxf(fmaf(s1.x, bf2f(x1[4]), h1v.x), 0.f));
    af1[5] = (short)f2bf(fmaxf(fmaf(s1.y, bf2f(x1[5]), h1v.y), 0.f));
    af1[6] = (short)f2bf(fmaxf(fmaf(s1.z, bf2f(x1[6]), h1v.z), 0.f));
    af1[7] = (short)f2bf(fmaxf(fmaf(s1.w, bf2f(x1[7]), h1v.w), 0.f));
#pragma unroll
    for (int n = 0; n < 8; ++n) {
      const bf16x8 bf =
          *(const bf16x8*)(W2b + (size_t)(n * 16 + l16) * DD + kb);
      acc2[0][n] = __builtin_amdgcn_mfma_f32_16x16x32_bf16(af0, bf, acc2[0][n], 0, 0, 0);
      acc2[1][n] = __builtin_amdgcn_mfma_f32_16x16x32_bf16(af1, bf, acc2[1][n], 0, 0, 0);
    }
  }
  // bias2 + BN2 replica stats
#pragma unroll
  for (int n = 0; n < 8; ++n) {
    const int col = n * 16 + l16;
    const float bv = b2[col];
    float sv = 0.f, qv = 0.f;
#pragma unroll
    for (int m = 0; m < 2; ++m)
#pragma unroll
      for (int r = 0; r < 4; ++r) {
        const float o = acc2[m][n][r] + bv;
        acc2[m][n][r] = o;
        if (rowq + m * 16 + r < NN) { sv += o; qv += o * o; }
      }
    sv += __shfl_xor(sv, 16); qv += __shfl_xor(qv, 16);
    sv += __shfl_xor(sv, 32); qv += __shfl_xor(qv, 32);
    if (quad == 0) {
      const int rep = (bk & (NREP - 1)) * DD;
      atomicAdd(&sum2r[rep + col], sv);
      atomicAdd(&sumsq2r[rep + col], qv);
    }
  }
  __syncthreads();  // stats drained
  if (tid == 0) amlast = (atomicAdd(&syncw[2], 1) == MLP_B - 1) ? 1 : 0;
  __syncthreads();
  if (amlast) {
    if (tid < DD) {
      float sm = 0.f, qm = 0.f;
#pragma unroll
      for (int r = 0; r < NREP; ++r) {
        sm += ldw(&sum2r[r * DD + tid]);
        qm += ldw(&sumsq2r[r * DD + tid]);
      }
      const float inv_n = 1.0f / (float)NN;
      const float mean = sm * inv_n;
      const float var = qm * inv_n - mean * mean;
      const float sc = g2[tid] * rsqrtf(var + BN_EPS);
      stw(&scale2[tid], sc);
      stw(&shift2[tid], be2[tid] - mean * sc);
      lsc[tid] = sc;
      lsh[tid] = be2[tid] - mean * sc;
    }
    __syncthreads();
    if (tid == 0)
      __hip_atomic_store(&syncw[3], 1, __ATOMIC_RELAXED, __HIP_MEMORY_SCOPE_AGENT);
  } else {
    if (tid == 0) {
      while (__hip_atomic_load(&syncw[3], __ATOMIC_RELAXED,
                               __HIP_MEMORY_SCOPE_AGENT) == 0)
        __builtin_amdgcn_s_sleep(8);
    }
    __syncthreads();
    if (tid < DD) {  // NORMAL loads
      lsc[tid] = scale2[tid];
      lsh[tid] = shift2[tid];
    }
  }
  __syncthreads();
  // BN2 + ReLU on fp32 acc -> out (d_out scratch all dead past flag2)
#pragma unroll
  for (int n = 0; n < 8; ++n) {
    const int col = n * 16 + l16;
    const float sc = lsc[col];
    const float sh = lsh[col];
#pragma unroll
    for (int m = 0; m < 2; ++m)
#pragma unroll
      for (int r = 0; r < 4; ++r) {
        const int row = rowq + m * 16 + r;
        if (row < NN)
          out[(size_t)row * DD + col] = fmaxf(fmaf(sc, acc2[m][n][r], sh), 0.f);
      }
  }
}

// ---------------------------------------------------------------------------
extern "C" void kernel_launch(void* const* d_in, const int* in_sizes, int n_in,
                              void* d_out, int out_size, void* d_ws, size_t ws_size,
                              hipStream_t stream) {
  const float* x = (const float*)d_in[0];
  const int* ei = (const int*)d_in[1];
  const float* eps = (const float*)d_in[2];
  const float* W1 = (const float*)d_in[3];
  const float* b1 = (const float*)d_in[4];
  const float* g1 = (const float*)d_in[5];
  const float* be1 = (const float*)d_in[6];
  const float* W2 = (const float*)d_in[7];
  const float* b2 = (const float*)d_in[8];
  const float* g2 = (const float*)d_in[9];
  const float* be2 = (const float*)d_in[10];
  float* out = (float*)d_out;

  const int* rows = ei;
  const int* cols = ei + EE;

  // d_out scratch (all dead before the final out write)
  int* rcnt = (int*)d_out;                                  // 200KB
  unsigned short* xq = (unsigned short*)d_out + 2000000;    // byte 4.0M, 12.8MB
  unsigned short* csr16 = (unsigned short*)((char*)d_out + 16800000);  // 6.4MB
  unsigned short* W1b = (unsigned short*)d_out + 11640000;  // byte 23.28M
  unsigned short* W2b = (unsigned short*)d_out + 11680000;  // byte 23.36M
  float* reps = (float*)d_out + 5875000;                    // byte 23.5M, 64KB
  float* sum1r = reps;
  float* sumsq1r = reps + NREP * DD;
  float* sum2r = reps + 2 * NREP * DD;
  float* sumsq2r = reps + 3 * NREP * DD;

  // d_ws: agg | stats/sync tail (never overwritten by out)
  unsigned short* aggb = (unsigned short*)d_ws;             // 12.8MB
  float* stf = (float*)((char*)d_ws + 12800000);
  float* scale1 = stf + 0;
  float* shift1 = stf + 128;
  float* scale2 = stf + 256;
  float* shift2 = stf + 384;
  int* syncw = (int*)(stf + 512);

  // 1. prep: x -> column-blocked bf16 xq, W1b/W2b, zero rcnt/reps/syncw
  k_prep<<<XCONV_B + 32, 256, 0, stream>>>(x, W1, W2, xq, W1b, W2b, rcnt, reps,
                                           syncw);
  // 2. CSR-fixed binning (row-sorted in one pass)
  k_binrow<<<BIN_BLOCKS, 256, 0, stream>>>(rows, cols, rcnt, csr16);
  // 3. pass-sliced pipelined gather -> aggb
  k_agg<<<4 * NAGG, 64, 0, stream>>>(xq, eps, rcnt, csr16, aggb);
  // 4. fused MLP: GEMM1+BN1+ReLU+GEMM2+BN2+ReLU -> fp32 out
  k_mlp<<<MLP_B, 256, 0, stream>>>(aggb, sum1r, sumsq1r, g1, be1, W1b, b1,
                                   W2b, b2, sum2r, sumsq2r, g2, be2, scale1,
                                   shift1, scale2, shift2, syncw, out);
}

// Round 6
// 208.968 us; speedup vs baseline: 1.1252x; 1.1252x over previous
//
#include <hip/hip_runtime.h>

#define NN 50000
#define EE 800000
#define DD 128
#define BN_EPS 1e-5f
#define XCONV_B 3125    // N*D/8/256
#define BIN_BLOCKS 200
#define BIN_EDGES 4000  // per block; 200*4000 == EE
#define NBUCK 3125      // 50000/16: 16-row buckets (exact)
#define BROWS 16
#define BCAP 512        // bucket capacity (mean 256, +16 sigma headroom)
#define NREP 32         // BN-stat replica count
#define GEMM_B 782      // ceil(NN/64) for gemm2
#define LDA 136         // padded LDS tile stride (bf16)
#define ZROW NN         // dummy zero row in xb (branchless gather padding)

typedef __attribute__((ext_vector_type(8))) short bf16x8;
typedef __attribute__((ext_vector_type(4))) float f32x4;
typedef __attribute__((ext_vector_type(8))) unsigned short u16x8;

__device__ inline unsigned short f2bf(float f) {  // RNE fp32 -> bf16
  unsigned int u = __float_as_uint(f);
  u = (u + 0x7fffu + ((u >> 16) & 1u)) >> 16;
  return (unsigned short)u;
}
__device__ inline float bf2f(unsigned short b) {
  return __uint_as_float(((unsigned int)b) << 16);
}
// clamped sorted-col fetch: OOB -> ZROW (zero row; adds 0.0 exactly)
__device__ inline int colof(const unsigned short* sc, int i, int e) {
  const unsigned short v = sc[i < e ? i : 0];
  return i < e ? (int)v : ZROW;
}

// ---------------------------------------------------------------------------
// R16 = best-proven structure (R3 kernels + R2 fused-stats gemm2) with ONE
// change: double-buffered gather. Lessons pinned: launch gap ~13-20us
// (R7-R9); __threadfence = L2 wb/inv storm (R12); in-kernel grid-sync/spin
// fusion = ~40us idle convoys, no win (R14/R15); shfl-addressed gather
// serializes load issue via lgkmcnt (R15); gather stuck at ~40cy/edge/CU
// across all concurrency shapes (R11-R15) -> diagnosis: compiler drains
// vmcnt each loop iter (no cross-backedge pipelining), ~5 gather-waves/CU
// give too few overlapped exposures. Fix: issue-before-consume double
// buffer with static register banks (partial vmcnt waits) + branchless
// full-width chunks via dummy zero row xb[50000].
// Memory (d_out scratch, dead before k_bnrelu overwrites):
//   [0,12.5KB)      bcur[NBUCK] + done[1]
//   [4.0M,16.80M+256) xb = bf16(x) rows 0..50000 (row 50000 = zeros)
//   [16.80M+256, 23.20M+256) bbuf u32[NBUCK*BCAP] packed (row&15)<<16|col
//   [23.28M,+32KB)  W1b; [23.36M,+32KB) W2b; [23.5M,+64KB) reps
// d_ws: h1b | h2b | scale2,shift2 tail. 5 dispatches.
// ---------------------------------------------------------------------------

// K0: fused prep — x->bf16 xb (+zero row), W1b, W2b, zero bcur+done+reps
__global__ __launch_bounds__(256) void k_prep(const float* __restrict__ x,
                                              const float* __restrict__ W1,
                                              const float* __restrict__ W2,
                                              unsigned short* __restrict__ xb,
                                              unsigned short* __restrict__ W1b,
                                              unsigned short* __restrict__ W2b,
                                              int* __restrict__ bcur,
                                              float* __restrict__ reps) {
  const int b = blockIdx.x;
  const int t = threadIdx.x;
  if (b < XCONV_B) {
    const int gid = b * 256 + t;
    const float4 v0 = ((const float4*)x)[gid * 2];
    const float4 v1 = ((const float4*)x)[gid * 2 + 1];
    ushort4 o0, o1;
    o0.x = f2bf(v0.x); o0.y = f2bf(v0.y); o0.z = f2bf(v0.z); o0.w = f2bf(v0.w);
    o1.x = f2bf(v1.x); o1.y = f2bf(v1.y); o1.z = f2bf(v1.z); o1.w = f2bf(v1.w);
    ((ushort4*)xb)[gid * 2] = o0;
    ((ushort4*)xb)[gid * 2 + 1] = o1;
    if (gid <= NBUCK) bcur[gid] = 0;  // includes done counter at [NBUCK]
    if (gid < 4 * NREP * DD) reps[gid] = 0.0f;
    if (gid < 16) {  // dummy zero row xb[50000]
      const ushort4 z = {0, 0, 0, 0};
      ((ushort4*)(xb + (size_t)NN * DD))[gid * 2] = z;
      ((ushort4*)(xb + (size_t)NN * DD))[gid * 2 + 1] = z;
    }
  } else if (b < XCONV_B + 16) {
    const int gid = (b - XCONV_B) * 256 + t;
    const float4 v = ((const float4*)W1)[gid];
    ushort4 o;
    o.x = f2bf(v.x); o.y = f2bf(v.y); o.z = f2bf(v.z); o.w = f2bf(v.w);
    ((ushort4*)W1b)[gid] = o;
  } else {
    const int gid = (b - XCONV_B - 16) * 256 + t;
    const float4 v = ((const float4*)W2)[gid];
    ushort4 o;
    o.x = f2bf(v.x); o.y = f2bf(v.y); o.z = f2bf(v.z); o.w = f2bf(v.w);
    ((ushort4*)W2b)[gid] = o;
  }
}

// K1: bin edges into fixed-capacity 16-row buckets (R3, proven)
__global__ __launch_bounds__(256) void k_bin0(const int* __restrict__ rows,
                                              const int* __restrict__ cols,
                                              int* __restrict__ bcur,
                                              unsigned int* __restrict__ bbuf) {
  __shared__ int hist[NBUCK];
  __shared__ int lbase[NBUCK];
  const int t = threadIdx.x;
  for (int i = t; i < NBUCK; i += 256) hist[i] = 0;
  __syncthreads();
  const int e0 = blockIdx.x * BIN_EDGES;
  int er[16], ec[16];
#pragma unroll
  for (int i = 0; i < 16; ++i) {
    const int idx = t + i * 256;
    if (idx < BIN_EDGES) {
      er[i] = rows[e0 + idx];
      ec[i] = cols[e0 + idx];
      atomicAdd(&hist[er[i] >> 4], 1);
    }
  }
  __syncthreads();
  for (int i = t; i < NBUCK; i += 256) {
    const int c = hist[i];
    lbase[i] = (c > 0) ? atomicAdd(&bcur[i], c) : 0;
    hist[i] = 0;
  }
  __syncthreads();
#pragma unroll
  for (int i = 0; i < 16; ++i) {
    const int idx = t + i * 256;
    if (idx < BIN_EDGES) {
      const int bk = er[i] >> 4;
      const int lp = lbase[bk] + atomicAdd(&hist[bk], 1);
      if (lp < BCAP)
        bbuf[(size_t)bk * BCAP + lp] =
            ((unsigned)(er[i] & 15) << 16) | (unsigned)ec[i];
    }
  }
}

// 8-load chunk issue (rows r0,r1; 4 edges each via sub-striding) + consume
#define ISSUE(P, Q, I0, I1)                                            \
  P##0 = *(const u16x8*)(xb + (size_t)colof(scols, (I0), end0) * DD + l16 * 8); \
  P##1 = *(const u16x8*)(xb + (size_t)colof(scols, (I0) + 4, end0) * DD + l16 * 8); \
  P##2 = *(const u16x8*)(xb + (size_t)colof(scols, (I0) + 8, end0) * DD + l16 * 8); \
  P##3 = *(const u16x8*)(xb + (size_t)colof(scols, (I0) + 12, end0) * DD + l16 * 8); \
  Q##0 = *(const u16x8*)(xb + (size_t)colof(scols, (I1), end1) * DD + l16 * 8); \
  Q##1 = *(const u16x8*)(xb + (size_t)colof(scols, (I1) + 4, end1) * DD + l16 * 8); \
  Q##2 = *(const u16x8*)(xb + (size_t)colof(scols, (I1) + 8, end1) * DD + l16 * 8); \
  Q##3 = *(const u16x8*)(xb + (size_t)colof(scols, (I1) + 12, end1) * DD + l16 * 8);

#define CONSUME(P, Q)                                                  \
  _Pragma("unroll") for (int j = 0; j < 8; ++j) {                      \
    a0[j] += (bf2f(P##0[j]) + bf2f(P##1[j])) +                         \
             (bf2f(P##2[j]) + bf2f(P##3[j]));                          \
    a1[j] += (bf2f(Q##0[j]) + bf2f(Q##1[j])) +                         \
             (bf2f(Q##2[j]) + bf2f(Q##3[j]));                          \
  }

// K2: FUSED per-bucket aggregation + GEMM1 (R3 structure; NEW gather core).
__global__ __launch_bounds__(128) void k_aggemm1(
    const unsigned short* __restrict__ xb, const float* __restrict__ eps,
    const int* __restrict__ bcnt, const unsigned int* __restrict__ bbuf,
    const unsigned short* __restrict__ W, const float* __restrict__ bias,
    unsigned short* __restrict__ outb, float* __restrict__ sum1r,
    float* __restrict__ sumsq1r) {
  __shared__ unsigned short scols[BCAP];      // 1KB sorted col ids
  __shared__ unsigned short sA[BROWS * LDA];  // 4.25KB padded A tile
  __shared__ int rcnt[BROWS];
  __shared__ int roff[BROWS + 1];
  const int t = threadIdx.x;
  const int bk = blockIdx.x;
  const int wv = t >> 6;       // 0..1
  const int lane = t & 63;
  const int sub = lane >> 4;   // 0..3
  const int l16 = lane & 15;

  int n = bcnt[bk];
  n = n < BCAP ? n : BCAP;
  if (t < BROWS) rcnt[t] = 0;
  __syncthreads();

  // ---- phase A1: load bucket entries + per-row count (R3, proven)
  unsigned int ent[4];
  int nl = 0;
  for (int i = t; i < n; i += 128) {
    const unsigned int e = bbuf[(size_t)bk * BCAP + i];
    ent[nl++] = e;
    atomicAdd(&rcnt[e >> 16], 1);
  }
  __syncthreads();
  if (t < BROWS) {
    int v = rcnt[t];
#pragma unroll
    for (int off = 1; off < BROWS; off <<= 1) {
      const int u = __shfl_up(v, off);
      if (lane >= off) v += u;
    }
    roff[t] = v - rcnt[t];
    if (t == BROWS - 1) roff[BROWS] = v;
    rcnt[t] = 0;
  }
  __syncthreads();
  for (int i = 0; i < nl; ++i) {
    const int r = ent[i] >> 16;
    const int pos = roff[r] + atomicAdd(&rcnt[r], 1);
    scols[pos] = (unsigned short)(ent[i] & 0xffffu);
  }
  __syncthreads();

  // ---- phase A2: row-pair gather, double-buffered 16-edge chunks,
  // branchless full width (OOB edges -> ZROW, add exact 0.0)
  {
    const float s = 1.0f + eps[0];
#pragma unroll
    for (int rr = 0; rr < 4; ++rr) {
      const int r0 = wv + rr * 4;
      const int r1 = r0 + 2;
      float a0[8], a1[8];
#pragma unroll
      for (int j = 0; j < 8; ++j) { a0[j] = 0.f; a1[j] = 0.f; }
      if (sub < 2) {  // self rows: sub0 -> r0, sub1 -> r1, scaled by 1+eps
        const int selfrow = bk * BROWS + (sub == 0 ? r0 : r1);
        const u16x8 a = *(const u16x8*)(xb + (size_t)selfrow * DD + l16 * 8);
        if (sub == 0) {
#pragma unroll
          for (int j = 0; j < 8; ++j) a0[j] = s * bf2f(a[j]);
        } else {
#pragma unroll
          for (int j = 0; j < 8; ++j) a1[j] = s * bf2f(a[j]);
        }
      }
      const int end0 = roff[r0 + 1];
      const int end1 = roff[r1 + 1];
      const int n0 = end0 - roff[r0];
      const int n1 = end1 - roff[r1];
      int i0 = roff[r0] + sub;
      int i1 = roff[r1] + sub;
      int nb = (n0 > n1 ? n0 : n1);
      nb = (nb + 15) >> 4;  // wave-uniform chunk count
      u16x8 pa0, pa1, pa2, pa3, qa0, qa1, qa2, qa3;  // bank A
      u16x8 pb0, pb1, pb2, pb3, qb0, qb1, qb2, qb3;  // bank B
      if (nb > 0) {
        ISSUE(pa, qa, i0, i1);
        i0 += 16; i1 += 16;
        int k = nb - 1;
        while (k >= 2) {  // 2x unrolled double-buffer: issue-next, consume-prev
          ISSUE(pb, qb, i0, i1);
          i0 += 16; i1 += 16;
          CONSUME(pa, qa);
          ISSUE(pa, qa, i0, i1);
          i0 += 16; i1 += 16;
          CONSUME(pb, qb);
          k -= 2;
        }
        if (k == 1) {
          ISSUE(pb, qb, i0, i1);
          CONSUME(pa, qa);
          CONSUME(pb, qb);
        } else {
          CONSUME(pa, qa);
        }
      }
#pragma unroll
      for (int j = 0; j < 8; ++j) {
        a0[j] += __shfl_xor(a0[j], 16);
        a0[j] += __shfl_xor(a0[j], 32);
        a1[j] += __shfl_xor(a1[j], 16);
        a1[j] += __shfl_xor(a1[j], 32);
      }
      if (sub < 2) {
        u16x8 o;
        if (sub == 0) {
#pragma unroll
          for (int j = 0; j < 8; ++j) o[j] = f2bf(a0[j]);
          *(u16x8*)(&sA[r0 * LDA + l16 * 8]) = o;
        } else {
#pragma unroll
          for (int j = 0; j < 8; ++j) o[j] = f2bf(a1[j]);
          *(u16x8*)(&sA[r1 * LDA + l16 * 8]) = o;
        }
      }
    }
  }
  __syncthreads();

  // ---- phase B: MFMA GEMM 16x128; wave wv owns cols [wv*64, +64) (R3)
  f32x4 acc[4];
#pragma unroll
  for (int nn = 0; nn < 4; ++nn) acc[nn] = (f32x4){0.f, 0.f, 0.f, 0.f};
#pragma unroll
  for (int kk = 0; kk < 4; ++kk) {
    const bf16x8 af = *(const bf16x8*)(&sA[l16 * LDA + kk * 32 + sub * 8]);
#pragma unroll
    for (int nn = 0; nn < 4; ++nn) {
      const bf16x8 bf = *(const bf16x8*)(
          W + (size_t)(wv * 64 + nn * 16 + l16) * DD + sub * 8 + kk * 32);
      acc[nn] = __builtin_amdgcn_mfma_f32_16x16x32_bf16(af, bf, acc[nn], 0, 0, 0);
    }
  }
  const int orow0 = bk * BROWS + sub * 4;
  const int rep = (bk & (NREP - 1)) * DD;
#pragma unroll
  for (int nn = 0; nn < 4; ++nn) {
    const int col = wv * 64 + nn * 16 + l16;
    const float bv = bias[col];
    float sv = 0.f, qv = 0.f;
#pragma unroll
    for (int r = 0; r < 4; ++r) {
      const float o = acc[nn][r] + bv;
      outb[(size_t)(orow0 + r) * DD + col] = f2bf(o);
      sv += o; qv += o * o;
    }
    sv += __shfl_xor(sv, 16); qv += __shfl_xor(qv, 16);
    sv += __shfl_xor(sv, 32); qv += __shfl_xor(qv, 32);
    if (sub == 0) {
      atomicAdd(&sum1r[rep + col], sv);
      atomicAdd(&sumsq1r[rep + col], qv);
    }
  }
}

// K3: GEMM2 with fused last-block BN2 collapse (R2, proven; fence-free)
__global__ __launch_bounds__(256) void k_gemm2(const unsigned short* __restrict__ A,
                                               const float* __restrict__ sum1r,
                                               const float* __restrict__ sumsq1r,
                                               const float* __restrict__ gamma,
                                               const float* __restrict__ beta,
                                               const unsigned short* __restrict__ W,
                                               const float* __restrict__ bias,
                                               unsigned short* __restrict__ outb,
                                               float* __restrict__ sum2r,
                                               float* __restrict__ sumsq2r,
                                               const float* __restrict__ gamma2,
                                               const float* __restrict__ beta2,
                                               float* __restrict__ scale2,
                                               float* __restrict__ shift2,
                                               int* __restrict__ done) {
  __shared__ float lsc[DD];
  __shared__ float lsh[DD];
  __shared__ float bsum[DD];
  __shared__ float bsq[DD];
  __shared__ int amlast;
  const int tid = threadIdx.x;
  const int wv = tid >> 6;
  const int lane = tid & 63;
  const int quad = lane >> 4;
  const int l16 = lane & 15;
  if (tid < DD) {
    float sm = 0.f, qm = 0.f;
#pragma unroll
    for (int r = 0; r < NREP; ++r) {
      sm += sum1r[r * DD + tid];
      qm += sumsq1r[r * DD + tid];
    }
    const float inv_n = 1.0f / (float)NN;
    const float mean = sm * inv_n;
    const float var = qm * inv_n - mean * mean;
    const float s = gamma[tid] * rsqrtf(var + BN_EPS);
    lsc[tid] = s;
    lsh[tid] = beta[tid] - mean * s;
    bsum[tid] = 0.f;
    bsq[tid] = 0.f;
  }
  __syncthreads();

  const int rowbase = blockIdx.x * 64 + wv * 16 + l16;
  const int arow = rowbase < NN ? rowbase : NN - 1;
  const unsigned short* aptr = A + (size_t)arow * DD + quad * 8;

  f32x4 acc[8];
#pragma unroll
  for (int n = 0; n < 8; ++n) acc[n] = (f32x4){0.f, 0.f, 0.f, 0.f};
#pragma unroll
  for (int kk = 0; kk < 4; ++kk) {
    const int kbase = kk * 32 + quad * 8;
    const u16x8 a = *(const u16x8*)(aptr + kk * 32);
    const float4 s0 = *(const float4*)&lsc[kbase];
    const float4 s1 = *(const float4*)&lsc[kbase + 4];
    const float4 h0 = *(const float4*)&lsh[kbase];
    const float4 h1 = *(const float4*)&lsh[kbase + 4];
    bf16x8 af;
    af[0] = (short)f2bf(fmaxf(fmaf(s0.x, bf2f(a[0]), h0.x), 0.f));
    af[1] = (short)f2bf(fmaxf(fmaf(s0.y, bf2f(a[1]), h0.y), 0.f));
    af[2] = (short)f2bf(fmaxf(fmaf(s0.z, bf2f(a[2]), h0.z), 0.f));
    af[3] = (short)f2bf(fmaxf(fmaf(s0.w, bf2f(a[3]), h0.w), 0.f));
    af[4] = (short)f2bf(fmaxf(fmaf(s1.x, bf2f(a[4]), h1.x), 0.f));
    af[5] = (short)f2bf(fmaxf(fmaf(s1.y, bf2f(a[5]), h1.y), 0.f));
    af[6] = (short)f2bf(fmaxf(fmaf(s1.z, bf2f(a[6]), h1.z), 0.f));
    af[7] = (short)f2bf(fmaxf(fmaf(s1.w, bf2f(a[7]), h1.w), 0.f));
#pragma unroll
    for (int n = 0; n < 8; ++n) {
      const bf16x8 bf =
          *(const bf16x8*)(W + (size_t)(n * 16 + l16) * DD + kbase);
      acc[n] = __builtin_amdgcn_mfma_f32_16x16x32_bf16(af, bf, acc[n], 0, 0, 0);
    }
  }
  const int orow0 = blockIdx.x * 64 + wv * 16 + quad * 4;
#pragma unroll
  for (int n = 0; n < 8; ++n) {
    const int col = n * 16 + l16;
    const float bv = bias[col];
    float sv = 0.f, qv = 0.f;
#pragma unroll
    for (int r = 0; r < 4; ++r) {
      const int row = orow0 + r;
      if (row < NN) {
        const float o = acc[n][r] + bv;
        outb[(size_t)row * DD + col] = f2bf(o);
        sv += o; qv += o * o;
      }
    }
    sv += __shfl_xor(sv, 16); qv += __shfl_xor(qv, 16);
    sv += __shfl_xor(sv, 32); qv += __shfl_xor(qv, 32);
    if (quad == 0) { atomicAdd(&bsum[col], sv); atomicAdd(&bsq[col], qv); }
  }
  __syncthreads();
  if (tid < DD) {
    const int rep = (blockIdx.x & (NREP - 1)) * DD;
    atomicAdd(&sum2r[rep + tid], bsum[tid]);
    atomicAdd(&sumsq2r[rep + tid], bsq[tid]);
  }
  // last-block BN2 collapse (fence-free: syncthreads drains vmcnt before
  // tid0's done-RMW; reader uses agent-scope atomic loads)
  __syncthreads();
  if (tid == 0) amlast = (atomicAdd(done, 1) == GEMM_B - 1) ? 1 : 0;
  __syncthreads();
  if (amlast) {
    if (tid < DD) {
      float sm = 0.f, qm = 0.f;
#pragma unroll
      for (int r = 0; r < NREP; ++r) {
        sm += __hip_atomic_load(&sum2r[r * DD + tid], __ATOMIC_RELAXED,
                                __HIP_MEMORY_SCOPE_AGENT);
        qm += __hip_atomic_load(&sumsq2r[r * DD + tid], __ATOMIC_RELAXED,
                                __HIP_MEMORY_SCOPE_AGENT);
      }
      const float inv_n = 1.0f / (float)NN;
      const float mean = sm * inv_n;
      const float var = qm * inv_n - mean * mean;
      const float sc = gamma2[tid] * rsqrtf(var + BN_EPS);
      scale2[tid] = sc;
      shift2[tid] = beta2[tid] - mean * sc;
    }
  }
}

// K4: final BN2 + ReLU -> fp32 out (proven)
__global__ __launch_bounds__(256) void k_bnrelu(const unsigned short* __restrict__ in,
                                                const float* __restrict__ scale,
                                                const float* __restrict__ shift,
                                                float* __restrict__ out) {
  __shared__ float lsc[DD];
  __shared__ float lsh[DD];
  const int t = threadIdx.x;
  if (t < DD) {
    lsc[t] = scale[t];
    lsh[t] = shift[t];
  }
  __syncthreads();
  const int gid = blockIdx.x * 256 + t;
  const int c = (gid & 15) * 8;
  const u16x8 a = ((const u16x8*)in)[gid];
  const float4 sc0 = *(const float4*)&lsc[c];
  const float4 sc1 = *(const float4*)&lsc[c + 4];
  const float4 sh0 = *(const float4*)&lsh[c];
  const float4 sh1 = *(const float4*)&lsh[c + 4];
  float4 o0, o1;
  o0.x = fmaxf(fmaf(sc0.x, bf2f(a[0]), sh0.x), 0.f);
  o0.y = fmaxf(fmaf(sc0.y, bf2f(a[1]), sh0.y), 0.f);
  o0.z = fmaxf(fmaf(sc0.z, bf2f(a[2]), sh0.z), 0.f);
  o0.w = fmaxf(fmaf(sc0.w, bf2f(a[3]), sh0.w), 0.f);
  o1.x = fmaxf(fmaf(sc1.x, bf2f(a[4]), sh1.x), 0.f);
  o1.y = fmaxf(fmaf(sc1.y, bf2f(a[5]), sh1.y), 0.f);
  o1.z = fmaxf(fmaf(sc1.z, bf2f(a[6]), sh1.z), 0.f);
  o1.w = fmaxf(fmaf(sc1.w, bf2f(a[7]), sh1.w), 0.f);
  ((float4*)out)[gid * 2] = o0;
  ((float4*)out)[gid * 2 + 1] = o1;
}

// ---------------------------------------------------------------------------
extern "C" void kernel_launch(void* const* d_in, const int* in_sizes, int n_in,
                              void* d_out, int out_size, void* d_ws, size_t ws_size,
                              hipStream_t stream) {
  const float* x = (const float*)d_in[0];
  const int* ei = (const int*)d_in[1];
  const float* eps = (const float*)d_in[2];
  const float* W1 = (const float*)d_in[3];
  const float* b1 = (const float*)d_in[4];
  const float* g1 = (const float*)d_in[5];
  const float* be1 = (const float*)d_in[6];
  const float* W2 = (const float*)d_in[7];
  const float* b2 = (const float*)d_in[8];
  const float* g2 = (const float*)d_in[9];
  const float* be2 = (const float*)d_in[10];
  float* out = (float*)d_out;

  const int* rows = ei;
  const int* cols = ei + EE;

  // d_out scratch (all dead before k_bnrelu writes d_out)
  int* bcur = (int*)d_out;                                  // NBUCK ints + done
  unsigned short* xb = (unsigned short*)d_out + 2000000;    // byte 4.0M (+zero row)
  unsigned int* bbuf = (unsigned int*)((char*)d_out + 16800256);  // 6.4MB
  unsigned short* W1b = (unsigned short*)d_out + 11640000;  // byte 23.28M
  unsigned short* W2b = (unsigned short*)d_out + 11680000;  // byte 23.36M
  float* reps = (float*)d_out + 5875000;                    // byte 23.5M, 64KB
  float* sum1r = reps;
  float* sumsq1r = reps + NREP * DD;
  float* sum2r = reps + 2 * NREP * DD;
  float* sumsq2r = reps + 3 * NREP * DD;
  int* done = bcur + NBUCK;

  unsigned short* h1b = (unsigned short*)d_ws;        // aggemm1 out
  unsigned short* h2b = h1b + (size_t)NN * DD;        // gemm2 out
  float* stats = (float*)(h1b + (size_t)2 * NN * DD); // 4KB tail of d_ws
  float* scale2 = stats + 0;
  float* shift2 = stats + 128;

  // 1. prep: x/W1/W2 -> bf16 (+zero row), zero bcur+done+reps
  k_prep<<<XCONV_B + 32, 256, 0, stream>>>(x, W1, W2, xb, W1b, W2b, bcur, reps);
  // 2. bin edges into fixed 16-row buckets
  k_bin0<<<BIN_BLOCKS, 256, 0, stream>>>(rows, cols, bcur, bbuf);
  // 3. FUSED sort + double-buffered gather + GEMM1 -> h1b, BN1 stats
  k_aggemm1<<<NBUCK, 128, 0, stream>>>(xb, eps, bcur, bbuf, W1b, b1, h1b,
                                       sum1r, sumsq1r);
  // 4. GEMM2 (BN1+ReLU on the fly) -> h2b; last block collapses BN2 stats
  k_gemm2<<<GEMM_B, 256, 0, stream>>>(h1b, sum1r, sumsq1r, g1, be1, W2b, b2,
                                      h2b, sum2r, sumsq2r, g2, be2,
                                      scale2, shift2, done);
  // 5. final BN2+ReLU -> fp32 out
  k_bnrelu<<<(NN * DD / 8) / 256, 256, 0, stream>>>(h2b, scale2, shift2, out);
}